// Round 10
// baseline (141.625 us; speedup 1.0000x reference)
//
#include <hip/hip_runtime.h>
#include <hip/hip_bf16.h>

// DynamicSlidingWindowAttention — flash attention, bf16 MFMA, gfx950.
// R10: LDS-bandwidth attack (R9 analysis: ~18 of 42 µs is LDS bank time).
//  * 32 q-rows per wave (2 fragment sets): kf read once -> 16 MFMA (both
//    sets); vf read once -> both sets' PV. Fragment bytes/unit-work ~halved.
//  * Staging via __builtin_amdgcn_global_load_lds width=16 (m97-verified):
//    swizzle moved to the SOURCE address (DMA dest is uniform-base+lane*16),
//    zero staging VGPRs/VALU.
//  * Block = 4 waves = 2 KV-groups x 2 waves; item = 64 q-rows (1024 items);
//    LDS 40960 B exactly -> 4 blocks/CU, 16 waves/CU, launch_bounds(256,4).
// Kept: work-stealing heavy-first, prestaged bf16 K/V^T in d_ws, static-max
// softmax in log2 domain, XOR-swizzled LDS reads (R8-validated).
// Layouts (m89/m91/m120-verified):
//   mfma_f32_16x16x32_bf16: A[m=lane&15][k=quad*8+j], B[k=quad*8+j][n=lane&15],
//   C/D: col=lane&15, row=quad*4+reg.

constexpr int Bc = 2, Hc = 16, Tc = 2048, Dc = 64;
constexpr int BQ = 64;
constexpr int BK = 64;
constexpr int N_ITEMS = Bc * Hc * (Tc / BQ);   // 1024
constexpr float QSCALE = 0.125f * 1.44269504088896340736f;  // 1/sqrt(d)*log2e
constexpr float CMAX = 16.0f;   // static softmax max (log2 domain)

// d_ws layout (bytes): [0,4) counter | [256,+8MiB) K bf16 | then V^T bf16
constexpr size_t KB_OFF = 256;
constexpr size_t VB_OFF = 256 + (size_t)Bc * Hc * Tc * Dc * 2;
constexpr int HEADE = Tc * Dc;

// LDS (ushort units), 40960 B exactly -> 4 blocks/CU:
//   K: g*4096   [0, 8192)      V: 8192 + g*4096  [8192, 16384)
//   P: 16384 + wave*1024       [16384, 20480)
// item broadcast overlays wave-0 P (dead at broadcast time).
constexpr int KOFF = 0;
constexpr int VOFF = 8192;
constexpr int POFF = 16384;

typedef __attribute__((ext_vector_type(8))) short short8;
typedef __attribute__((ext_vector_type(4))) float float4v;

#if defined(__has_builtin)
#if __has_builtin(__builtin_amdgcn_exp2f)
#define EXP2 __builtin_amdgcn_exp2f
#endif
#endif
#ifndef EXP2
#define EXP2 exp2f
#endif

__device__ inline unsigned f2bf_u(float f) {
    union { float f; unsigned u; } v; v.f = f;
    return (v.u + 0x7fffu + ((v.u >> 16) & 1u)) >> 16;   // RNE
}

__device__ inline short8 pack8(const float* t) {
    short8 r;
#pragma unroll
    for (int j = 0; j < 8; j++) r[j] = (short)f2bf_u(t[j]);
    return r;
}

__device__ inline unsigned pk_bf16(float a, float b) {
    __hip_bfloat162 h = __float22bfloat162_rn(make_float2(a, b));
    union { __hip_bfloat162 h; unsigned u; } v; v.h = h;
    return v.u;
}

// async global->LDS, 16 B/lane; dest = uniform base + lane*16 (m97/m104).
__device__ inline void dma16(const unsigned short* g, unsigned short* l) {
    __builtin_amdgcn_global_load_lds(
        (const __attribute__((address_space(1))) unsigned int*)g,
        (__attribute__((address_space(3))) unsigned int*)l, 16, 0, 0);
}

// ---- pre-pass: K convert + V transpose-convert ----
__global__ __launch_bounds__(256)
void preconv_kernel(const float* __restrict__ K, const float* __restrict__ V,
                    unsigned short* __restrict__ Kb, unsigned short* __restrict__ Vtb) {
    const int blk = blockIdx.x;
    const int tid = threadIdx.x;
    if (blk < 2048) {
        const int base = blk * 2048 + tid * 8;
        float4v a = *(const float4v*)(K + base);
        float4v b = *(const float4v*)(K + base + 4);
        float t[8] = {a[0], a[1], a[2], a[3], b[0], b[1], b[2], b[3]};
        *(short8*)(Kb + base) = pack8(t);
    } else {
        __shared__ float tile[64][65];
        const int blk2 = blk - 2048;
        const int bh = blk2 >> 5;
        const int t0 = (blk2 & 31) * 64;
        const float* src = V + (size_t)bh * HEADE + (size_t)t0 * Dc;
#pragma unroll
        for (int i = 0; i < 4; i++) {
            const int r = (tid >> 4) + i * 16;
            const int d4 = (tid & 15) * 4;
            float4v v4 = *(const float4v*)(src + r * Dc + d4);
            tile[r][d4] = v4[0]; tile[r][d4 + 1] = v4[1];
            tile[r][d4 + 2] = v4[2]; tile[r][d4 + 3] = v4[3];
        }
        __syncthreads();
        unsigned short* dst = Vtb + (size_t)bh * HEADE + t0;
#pragma unroll
        for (int i = 0; i < 2; i++) {
            const int d = (tid >> 3) + 32 * i;
            const int c = tid & 7;
            float t[8];
#pragma unroll
            for (int j = 0; j < 8; j++) t[j] = tile[c * 8 + j][d];
            *(short8*)(dst + (size_t)d * Tc + c * 8) = pack8(t);
        }
    }
}

__global__ __launch_bounds__(256, 4)
void dswa_kernel(const float* __restrict__ Q,
                 const unsigned short* __restrict__ Kb,
                 const unsigned short* __restrict__ Vtb,
                 const int* __restrict__ wsz,
                 float* __restrict__ O, unsigned* __restrict__ counter) {
    __shared__ __align__(16) unsigned short LDS[20480];   // 40960 B

    const int tid  = threadIdx.x;
    const int wave = tid >> 6;          // 0..3
    const int g    = wave >> 1;         // kv-split group 0/1
    const int wq   = wave & 1;          // 32-row q half
    const int lane = tid & 63;
    const int quad = lane >> 4;
    const int l16  = lane & 15;
    const int sw8  = (l16 & 7) << 3;    // fragment-read swizzle term

    unsigned short* Kl = &LDS[KOFF + g * 4096];
    unsigned short* Vt = &LDS[VOFF + g * 4096];
    unsigned short* Pl = &LDS[POFF + wave * 1024];
    int* ib = (int*)&LDS[POFF];

    // DMA source swizzle terms (per lane, constant across tiles/items):
    const int lrow = lane >> 3;                       // row-in-8 within issue
    const int lcol = ((lane & 7) * 8) ^ ((lrow & 7) << 3);

    for (;;) {
        if (tid == 0) *ib = (int)atomicAdd(counter, 1u);
        __syncthreads();
        const int idx = *ib;
        if (idx >= N_ITEMS) break;

        // heavy-first: h descending (largest window first), qt descending
        const int b  = idx & 1;
        const int qt = 31 - ((idx >> 1) & 31);
        const int h  = 15 - (idx >> 6);
        const int q0 = qt * BQ;
        const int win = wsz[h];

        const size_t headoff = (size_t)(b * Hc + h) * HEADE;
        const float* Qp = Q + headoff;
        const unsigned short* Kbh = Kb + headoff;
        const unsigned short* Vbh = Vtb + headoff;
        float* Op = O + headoff;

        // ---- Q fragments for both 16-row sets, pre-scaled (log2 domain) ----
        short8 qf[2][2];
#pragma unroll
        for (int s = 0; s < 2; s++) {
            const int qrow = q0 + wq * 32 + s * 16 + l16;
#pragma unroll
            for (int c = 0; c < 2; c++) {
                const float* src = Qp + (size_t)qrow * Dc + c * 32 + quad * 8;
                float4v a = *(const float4v*)src;
                float4v d4 = *(const float4v*)(src + 4);
                float t[8] = {a[0]*QSCALE, a[1]*QSCALE, a[2]*QSCALE, a[3]*QSCALE,
                              d4[0]*QSCALE, d4[1]*QSCALE, d4[2]*QSCALE, d4[3]*QSCALE};
                qf[s][c] = pack8(t);
            }
        }

        float4v acc[2][4];   // [set][nb], unnormalized O
#pragma unroll
        for (int s = 0; s < 2; s++)
#pragma unroll
            for (int nb = 0; nb < 4; nb++) acc[s][nb] = (float4v){0.f, 0.f, 0.f, 0.f};
        float lp0 = 0.0f, lp1 = 0.0f;   // per-lane l partials (row = l16 of set)

        const int kv_lo = (max(0, q0 - win)) & ~(BK - 1);
        const int n_tiles = (q0 + BQ - kv_lo) >> 6;
        const int IT = (n_tiles + 1) >> 1;

        // per-lane DMA source pointers for this group's first tile
        const int kv0g = kv_lo + g * BK;
        const unsigned short* kgp = Kbh + (size_t)(kv0g + wq * 32 + lrow) * 64 + lcol;
        const unsigned short* vgp = Vbh + (size_t)(wq * 32 + lrow) * Tc + kv0g + lcol;

        for (int t = 0; t < IT; ++t) {
            const int ti = g + 2 * t;
            const bool act = ti < n_tiles;
            const int kv0 = kv_lo + ti * BK;

            __syncthreads();   // everyone done reading prev tile's LDS

            if (act) {
                // stage K (4 issues) + V (4 issues): dest uniform-base+lane*16
#pragma unroll
                for (int j = 0; j < 4; j++)
                    dma16(kgp + j * 512, &Kl[wq * 2048 + j * 512]);
#pragma unroll
                for (int j = 0; j < 4; j++)
                    dma16(vgp + (size_t)j * 8 * Tc, &Vt[wq * 2048 + j * 512]);
            }
            __asm__ volatile("" ::: "memory");
            __builtin_amdgcn_s_waitcnt(0x0f70);   // vmcnt(0) only
            __asm__ volatile("" ::: "memory");
            __syncthreads();   // staging visible group-wide

            if (act) {
                // ---- kf once -> QK for BOTH sets (16 MFMA), then kf dies ----
                float4v sT0[4], sT1[4];
#pragma unroll
                for (int mb = 0; mb < 4; mb++) {
                    float4v c0 = {-CMAX, -CMAX, -CMAX, -CMAX};
                    float4v c1 = {-CMAX, -CMAX, -CMAX, -CMAX};
#pragma unroll
                    for (int ch = 0; ch < 2; ch++) {
                        short8 kf = *(short8*)&Kl[(mb * 16 + l16) * 64 +
                                                  ((ch * 32 + quad * 8) ^ sw8)];
                        c0 = __builtin_amdgcn_mfma_f32_16x16x32_bf16(kf, qf[0][ch], c0, 0, 0, 0);
                        c1 = __builtin_amdgcn_mfma_f32_16x16x32_bf16(kf, qf[1][ch], c1, 0, 0, 0);
                    }
                    sT0[mb] = c0; sT1[mb] = c1;
                }

                // ---- softmax set0 -> P -> pf0 ----
                short8 pf0[2], pf1[2];
                {
                    const int rs = q0 + wq * 32;
                    const bool interior = (rs >= kv0 + 63) && (rs + 15 - kv0 <= win);
                    if (!interior) {
                        const int dbase = rs + l16 - kv0 - quad * 4;
#pragma unroll
                        for (int mb = 0; mb < 4; mb++)
#pragma unroll
                            for (int r = 0; r < 4; r++) {
                                const unsigned diff = (unsigned)(dbase - mb * 16 - r);
                                sT0[mb][r] = (diff <= (unsigned)win) ? sT0[mb][r] : -3.0e38f;
                            }
                    }
#pragma unroll
                    for (int mb = 0; mb < 4; mb++) {
                        float p0 = EXP2(sT0[mb][0]);
                        float p1 = EXP2(sT0[mb][1]);
                        float p2 = EXP2(sT0[mb][2]);
                        float p3 = EXP2(sT0[mb][3]);
                        lp0 += (p0 + p1) + (p2 + p3);
                        unsigned* dst = (unsigned*)&Pl[l16 * 64 + ((mb * 16 + quad * 4) ^ sw8)];
                        dst[0] = pk_bf16(p0, p1);
                        dst[1] = pk_bf16(p2, p3);
                    }
                    __asm__ volatile("" ::: "memory");
#pragma unroll
                    for (int ch = 0; ch < 2; ch++)
                        pf0[ch] = *(short8*)&Pl[l16 * 64 + ((ch * 32 + quad * 8) ^ sw8)];
                }
                // ---- softmax set1 -> P (same 2 KB, after pf0 read) -> pf1 ----
                {
                    const int rs = q0 + wq * 32 + 16;
                    const bool interior = (rs >= kv0 + 63) && (rs + 15 - kv0 <= win);
                    if (!interior) {
                        const int dbase = rs + l16 - kv0 - quad * 4;
#pragma unroll
                        for (int mb = 0; mb < 4; mb++)
#pragma unroll
                            for (int r = 0; r < 4; r++) {
                                const unsigned diff = (unsigned)(dbase - mb * 16 - r);
                                sT1[mb][r] = (diff <= (unsigned)win) ? sT1[mb][r] : -3.0e38f;
                            }
                    }
                    __asm__ volatile("" ::: "memory");
#pragma unroll
                    for (int mb = 0; mb < 4; mb++) {
                        float p0 = EXP2(sT1[mb][0]);
                        float p1 = EXP2(sT1[mb][1]);
                        float p2 = EXP2(sT1[mb][2]);
                        float p3 = EXP2(sT1[mb][3]);
                        lp1 += (p0 + p1) + (p2 + p3);
                        unsigned* dst = (unsigned*)&Pl[l16 * 64 + ((mb * 16 + quad * 4) ^ sw8)];
                        dst[0] = pk_bf16(p0, p1);
                        dst[1] = pk_bf16(p2, p3);
                    }
                    __asm__ volatile("" ::: "memory");
#pragma unroll
                    for (int ch = 0; ch < 2; ch++)
                        pf1[ch] = *(short8*)&Pl[l16 * 64 + ((ch * 32 + quad * 8) ^ sw8)];
                }

                // ---- PV: vf read once, used by both sets ----
#pragma unroll
                for (int nb = 0; nb < 4; nb++) {
#pragma unroll
                    for (int ch = 0; ch < 2; ch++) {
                        short8 vf = *(short8*)&Vt[(nb * 16 + l16) * 64 +
                                                  ((ch * 32 + quad * 8) ^ sw8)];
                        acc[0][nb] = __builtin_amdgcn_mfma_f32_16x16x32_bf16(pf0[ch], vf, acc[0][nb], 0, 0, 0);
                        acc[1][nb] = __builtin_amdgcn_mfma_f32_16x16x32_bf16(pf1[ch], vf, acc[1][nb], 0, 0, 0);
                    }
                }
            }
            // advance DMA pointers (group stride = 2 tiles = 128 keys)
            kgp += 128 * 64;
            vgp += 128;
        }

        // ---- l: cross-quad reduce (every lane gets its row's full sum) ----
        lp0 += __shfl_xor(lp0, 16); lp0 += __shfl_xor(lp0, 32);
        lp1 += __shfl_xor(lp1, 16); lp1 += __shfl_xor(lp1, 32);

        // ---- merge the two KV-split partials (pure adds), store ----
        __syncthreads();
        float* fl = (float*)LDS;   // 64 rows x stride 66 (overlays K/V bufs)
        if (g == 1) {
#pragma unroll
            for (int s = 0; s < 2; s++) {
                if (quad == 0) fl[(wq * 32 + s * 16 + l16) * 66 + 64] = (s ? lp1 : lp0);
#pragma unroll
                for (int r = 0; r < 4; r++) {
                    const int row = wq * 32 + s * 16 + quad * 4 + r;
#pragma unroll
                    for (int nb = 0; nb < 4; nb++)
                        fl[row * 66 + nb * 16 + l16] = acc[s][nb][r];
                }
            }
        }
        __syncthreads();
        if (g == 0) {
#pragma unroll
            for (int s = 0; s < 2; s++) {
                const float lps = s ? lp1 : lp0;
#pragma unroll
                for (int r = 0; r < 4; r++) {
                    const int row = wq * 32 + s * 16 + quad * 4 + r;
                    const float l0 = __shfl(lps, quad * 4 + r);
                    const float lt = l0 + fl[row * 66 + 64];
                    const float inv = 1.0f / lt;
                    float* dst = Op + (size_t)(q0 + row) * Dc;
#pragma unroll
                    for (int nb = 0; nb < 4; nb++)
                        dst[nb * 16 + l16] = (acc[s][nb][r] + fl[row * 66 + nb * 16 + l16]) * inv;
                }
            }
        }
        // next item's post-atomic barrier protects fl before reuse
    }
}

extern "C" void kernel_launch(void* const* d_in, const int* in_sizes, int n_in,
                              void* d_out, int out_size, void* d_ws, size_t ws_size,
                              hipStream_t stream) {
    (void)in_sizes; (void)n_in; (void)ws_size; (void)out_size;
    const float* Q = (const float*)d_in[0];
    const float* K = (const float*)d_in[1];
    const float* V = (const float*)d_in[2];
    const int* wsz = (const int*)d_in[3];
    float* Out = (float*)d_out;

    unsigned* counter = (unsigned*)d_ws;
    unsigned short* Kb  = (unsigned short*)((char*)d_ws + KB_OFF);
    unsigned short* Vtb = (unsigned short*)((char*)d_ws + VB_OFF);

    hipMemsetAsync(counter, 0, sizeof(unsigned), stream);
    preconv_kernel<<<dim3(3072), dim3(256), 0, stream>>>(K, V, Kb, Vtb);
    // 1024 blocks = 4 blocks/CU x 256 CU (LDS 40960 B); work-stealing body.
    dswa_kernel<<<dim3(1024), dim3(256), 0, stream>>>(Q, Kb, Vtb, wsz, Out, counter);
}

// Round 11
// 125.713 us; speedup vs baseline: 1.1266x; 1.1266x over previous
//
#include <hip/hip_runtime.h>
#include <hip/hip_bf16.h>

// DynamicSlidingWindowAttention — flash attention, bf16 MFMA, gfx950.
// R11: 32-key tiles unlock all proven wins simultaneously:
//  * 32 q-rows/wave (2 fragment sets): kf/vf LDS reads per pair halved.
//  * Single-barrier double-buffered staging (R9) w/ register prefetch
//    (16 VGPRs; consumed before the barrier -> barrier drain is lgkm-only).
//  * LDS = 40960 B exactly -> 4 blocks/CU; grid 1024 = ALL items resident
//    -> static decode, no atomics/broadcast, 1 barrier per 64 keys.
//  * 2-way KV split retained (item = 64 q-rows, critical path halved).
// R10 lesson: DMA staging w/o double-buffer serializes on vmcnt(0) — reverted
// to register prefetch. R7 lesson: VGPR cap >= 128 (launch_bounds(256,4)).
// Layouts (m89/m91/m120-verified):
//   mfma_f32_16x16x32_bf16: A[m=lane&15][k=quad*8+j], B[k=quad*8+j][n=lane&15],
//   C/D: col=lane&15, row=quad*4+reg.

constexpr int Bc = 2, Hc = 16, Tc = 2048, Dc = 64;
constexpr int BQ = 64;            // q rows per block/item
constexpr int BK = 32;            // keys per kv tile (halved)
constexpr float QSCALE = 0.125f * 1.44269504088896340736f;  // 1/sqrt(d)*log2e
constexpr float CMAX = 16.0f;     // static softmax max (log2 domain)

// d_ws layout (bytes): [256,+8MiB) K bf16 | then V^T bf16 (counter removed)
constexpr size_t KB_OFF = 256;
constexpr size_t VB_OFF = 256 + (size_t)Bc * Hc * Tc * Dc * 2;
constexpr int HEADE = Tc * Dc;

// LDS (ushort units), 40960 B exactly -> 4 blocks/CU:
//   K: g*4096 + buf*2048          [0, 8192)       32x64, swizzle (row&7)<<3
//   V: 8192 + g*5120 + buf*2560   [8192, 18432)   64x40 (stride-40 pad)
//   P: 18432 + wave*512           [18432, 20480)  16x32, swizzle (l16&3)<<3
constexpr int KOFF = 0;
constexpr int VOFF = 8192;
constexpr int POFF = 18432;

typedef __attribute__((ext_vector_type(8))) short short8;
typedef __attribute__((ext_vector_type(4))) float float4v;

#if defined(__has_builtin)
#if __has_builtin(__builtin_amdgcn_exp2f)
#define EXP2 __builtin_amdgcn_exp2f
#endif
#endif
#ifndef EXP2
#define EXP2 exp2f
#endif

__device__ inline unsigned f2bf_u(float f) {
    union { float f; unsigned u; } v; v.f = f;
    return (v.u + 0x7fffu + ((v.u >> 16) & 1u)) >> 16;   // RNE
}

__device__ inline short8 pack8(const float* t) {
    short8 r;
#pragma unroll
    for (int j = 0; j < 8; j++) r[j] = (short)f2bf_u(t[j]);
    return r;
}

__device__ inline unsigned pk_bf16(float a, float b) {
    __hip_bfloat162 h = __float22bfloat162_rn(make_float2(a, b));
    union { __hip_bfloat162 h; unsigned u; } v; v.h = h;
    return v.u;
}

// ---- pre-pass: K convert + V transpose-convert (unchanged, proven) ----
__global__ __launch_bounds__(256)
void preconv_kernel(const float* __restrict__ K, const float* __restrict__ V,
                    unsigned short* __restrict__ Kb, unsigned short* __restrict__ Vtb) {
    const int blk = blockIdx.x;
    const int tid = threadIdx.x;
    if (blk < 2048) {
        const int base = blk * 2048 + tid * 8;
        float4v a = *(const float4v*)(K + base);
        float4v b = *(const float4v*)(K + base + 4);
        float t[8] = {a[0], a[1], a[2], a[3], b[0], b[1], b[2], b[3]};
        *(short8*)(Kb + base) = pack8(t);
    } else {
        __shared__ float tile[64][65];
        const int blk2 = blk - 2048;
        const int bh = blk2 >> 5;
        const int t0 = (blk2 & 31) * 64;
        const float* src = V + (size_t)bh * HEADE + (size_t)t0 * Dc;
#pragma unroll
        for (int i = 0; i < 4; i++) {
            const int r = (tid >> 4) + i * 16;
            const int d4 = (tid & 15) * 4;
            float4v v4 = *(const float4v*)(src + r * Dc + d4);
            tile[r][d4] = v4[0]; tile[r][d4 + 1] = v4[1];
            tile[r][d4 + 2] = v4[2]; tile[r][d4 + 3] = v4[3];
        }
        __syncthreads();
        unsigned short* dst = Vtb + (size_t)bh * HEADE + t0;
#pragma unroll
        for (int i = 0; i < 2; i++) {
            const int d = (tid >> 3) + 32 * i;
            const int c = tid & 7;
            float t[8];
#pragma unroll
            for (int j = 0; j < 8; j++) t[j] = tile[c * 8 + j][d];
            *(short8*)(dst + (size_t)d * Tc + c * 8) = pack8(t);
        }
    }
}

__global__ __launch_bounds__(256, 4)
void dswa_kernel(const float* __restrict__ Q,
                 const unsigned short* __restrict__ Kb,
                 const unsigned short* __restrict__ Vtb,
                 const int* __restrict__ wsz,
                 float* __restrict__ O) {
    __shared__ __align__(16) unsigned short LDS[20480];   // 40960 B exactly

    const int tid  = threadIdx.x;
    const int wave = tid >> 6;          // 0..3
    const int g    = wave >> 1;         // kv-split group 0/1
    const int wq   = wave & 1;          // 32-row q half
    const int lane = tid & 63;
    const int quad = lane >> 4;
    const int l16  = lane & 15;
    const int ksw  = 0;  (void)ksw;
    const int psw  = (l16 & 3) << 3;    // P swizzle term

    unsigned short* Kg = &LDS[KOFF + g * 4096];   // + buf*2048
    unsigned short* Vg = &LDS[VOFF + g * 5120];   // + buf*2560
    unsigned short* Pl = &LDS[POFF + wave * 512];

    // staging lane->chunk mapping (per group: 128 lanes stage K 4 KB + V 4 KB)
    const int l128 = tid & 127;
    const int krow = l128 >> 2;              // 0..31
    const int kcol = (l128 & 3) * 16;        // granule pair base (shorts)
    const int vrow = l128 >> 1;              // 0..63
    const int vcol = (l128 & 1) * 16;

    // ---- static item decode (heavy-first is free insurance) ----
    const int blk = blockIdx.x;
    const int b  = blk & 1;
    const int qt = 31 - ((blk >> 1) & 31);
    const int h  = 15 - (blk >> 6);
    const int q0 = qt * BQ;
    const int win = wsz[h];

    const size_t headoff = (size_t)(b * Hc + h) * HEADE;
    const float* Qp = Q + headoff;
    const unsigned short* Kbh = Kb + headoff;
    const unsigned short* Vbh = Vtb + headoff;
    float* Op = O + headoff;

    // ---- Q fragments for both 16-row sets, pre-scaled (log2 domain) ----
    short8 qf[2][2];
#pragma unroll
    for (int s = 0; s < 2; s++) {
        const int qrow = q0 + wq * 32 + s * 16 + l16;
#pragma unroll
        for (int c = 0; c < 2; c++) {
            const float* src = Qp + (size_t)qrow * Dc + c * 32 + quad * 8;
            float4v a = *(const float4v*)src;
            float4v d4 = *(const float4v*)(src + 4);
            float t[8] = {a[0]*QSCALE, a[1]*QSCALE, a[2]*QSCALE, a[3]*QSCALE,
                          d4[0]*QSCALE, d4[1]*QSCALE, d4[2]*QSCALE, d4[3]*QSCALE};
            qf[s][c] = pack8(t);
        }
    }

    float4v acc[2][4];   // [set][nb] unnormalized O
#pragma unroll
    for (int s = 0; s < 2; s++)
#pragma unroll
        for (int nb = 0; nb < 4; nb++) acc[s][nb] = (float4v){0.f, 0.f, 0.f, 0.f};
    float lp0 = 0.0f, lp1 = 0.0f;

    const int kv_lo = (max(0, q0 - win)) & ~(BK - 1);
    const int n_tiles = (q0 + BQ - kv_lo) >> 5;   // 32-key tiles
    const int IT = (n_tiles + 1) >> 1;

    // per-lane global source pointers (advance 2 tiles = 64 keys per iter)
    const int kv0g = kv_lo + g * BK;
    const unsigned short* kgp = Kbh + (size_t)(kv0g + krow) * Dc + kcol;
    const unsigned short* vgp = Vbh + (size_t)vrow * Tc + kv0g + vcol;

    // ---- prologue prefetch: tile g ----
    short8 kr0, kr1, vr0, vr1;
    if (g < n_tiles) {
        kr0 = *(const short8*)(kgp);
        kr1 = *(const short8*)(kgp + 8);
        vr0 = *(const short8*)(vgp);
        vr1 = *(const short8*)(vgp + 8);
    }
    kgp += 64 * Dc; vgp += 64;

    for (int t = 0; t < IT; ++t) {
        const int ti = g + 2 * t;
        const bool act = ti < n_tiles;
        const int kv0 = kv_lo + ti * BK;
        unsigned short* Kl = Kg + (t & 1) * 2048;
        unsigned short* Vt = Vg + (t & 1) * 2560;

        // ---- stage tile ti into buf[t&1] (consumes prefetch regs) ----
        if (act) {
            const int ks = (krow & 7) << 3;
            *(short8*)&Kl[krow * 64 + (kcol ^ ks)] = kr0;
            *(short8*)&Kl[krow * 64 + ((kcol + 8) ^ ks)] = kr1;
            *(short8*)&Vt[vrow * 40 + vcol] = vr0;
            *(short8*)&Vt[vrow * 40 + vcol + 8] = vr1;
        }
        // single rendezvous/tile; prefetch already consumed -> lgkm-only drain
        __syncthreads();

        // ---- prefetch next visit (flies during this tile's compute) ----
        if (ti + 2 < n_tiles) {
            kr0 = *(const short8*)(kgp);
            kr1 = *(const short8*)(kgp + 8);
            vr0 = *(const short8*)(vgp);
            vr1 = *(const short8*)(vgp + 8);
        }
        kgp += 64 * Dc; vgp += 64;

        if (act) {
            // ---- S^T = K Q^T - CMAX, both sets share kf (2 mb x 2 ch) ----
            float4v sT0[2], sT1[2];
#pragma unroll
            for (int mb = 0; mb < 2; mb++) {
                float4v c0 = {-CMAX, -CMAX, -CMAX, -CMAX};
                float4v c1 = {-CMAX, -CMAX, -CMAX, -CMAX};
#pragma unroll
                for (int ch = 0; ch < 2; ch++) {
                    const int row = mb * 16 + l16;
                    short8 kf = *(short8*)&Kl[row * 64 +
                                              ((ch * 32 + quad * 8) ^ ((row & 7) << 3))];
                    c0 = __builtin_amdgcn_mfma_f32_16x16x32_bf16(kf, qf[0][ch], c0, 0, 0, 0);
                    c1 = __builtin_amdgcn_mfma_f32_16x16x32_bf16(kf, qf[1][ch], c1, 0, 0, 0);
                }
                sT0[mb] = c0; sT1[mb] = c1;
            }

            // ---- set 0: mask, exp, P write, pf0 ----
            short8 pf0, pf1;
            {
                const int rs = q0 + wq * 32;
                const bool interior = (kv0 + 31 <= rs) && (rs + 15 - kv0 <= win);
                if (!interior) {
                    const int dbase = rs + l16 - kv0 - quad * 4;
#pragma unroll
                    for (int mb = 0; mb < 2; mb++)
#pragma unroll
                        for (int r = 0; r < 4; r++) {
                            const unsigned diff = (unsigned)(dbase - mb * 16 - r);
                            sT0[mb][r] = (diff <= (unsigned)win) ? sT0[mb][r] : -3.0e38f;
                        }
                }
#pragma unroll
                for (int mb = 0; mb < 2; mb++) {
                    float p0 = EXP2(sT0[mb][0]);
                    float p1 = EXP2(sT0[mb][1]);
                    float p2 = EXP2(sT0[mb][2]);
                    float p3 = EXP2(sT0[mb][3]);
                    lp0 += (p0 + p1) + (p2 + p3);
                    unsigned* dst = (unsigned*)&Pl[l16 * 32 + ((mb * 16 + quad * 4) ^ psw)];
                    dst[0] = pk_bf16(p0, p1);
                    dst[1] = pk_bf16(p2, p3);
                }
                __asm__ volatile("" ::: "memory");
                pf0 = *(short8*)&Pl[l16 * 32 + ((quad * 8) ^ psw)];
            }
            // ---- set 1: same P slot after pf0 read ----
            {
                const int rs = q0 + wq * 32 + 16;
                const bool interior = (kv0 + 31 <= rs) && (rs + 15 - kv0 <= win);
                if (!interior) {
                    const int dbase = rs + l16 - kv0 - quad * 4;
#pragma unroll
                    for (int mb = 0; mb < 2; mb++)
#pragma unroll
                        for (int r = 0; r < 4; r++) {
                            const unsigned diff = (unsigned)(dbase - mb * 16 - r);
                            sT1[mb][r] = (diff <= (unsigned)win) ? sT1[mb][r] : -3.0e38f;
                        }
                }
                __asm__ volatile("" ::: "memory");
#pragma unroll
                for (int mb = 0; mb < 2; mb++) {
                    float p0 = EXP2(sT1[mb][0]);
                    float p1 = EXP2(sT1[mb][1]);
                    float p2 = EXP2(sT1[mb][2]);
                    float p3 = EXP2(sT1[mb][3]);
                    lp1 += (p0 + p1) + (p2 + p3);
                    unsigned* dst = (unsigned*)&Pl[l16 * 32 + ((mb * 16 + quad * 4) ^ psw)];
                    dst[0] = pk_bf16(p0, p1);
                    dst[1] = pk_bf16(p2, p3);
                }
                __asm__ volatile("" ::: "memory");
                pf1 = *(short8*)&Pl[l16 * 32 + ((quad * 8) ^ psw)];
            }

            // ---- PV: vf read once serves both sets (K-dim 32 = 1 MFMA) ----
#pragma unroll
            for (int nb = 0; nb < 4; nb++) {
                short8 vf = *(short8*)&Vt[(nb * 16 + l16) * 40 + quad * 8];
                acc[0][nb] = __builtin_amdgcn_mfma_f32_16x16x32_bf16(pf0, vf, acc[0][nb], 0, 0, 0);
                acc[1][nb] = __builtin_amdgcn_mfma_f32_16x16x32_bf16(pf1, vf, acc[1][nb], 0, 0, 0);
            }
        }
    }

    // ---- l: cross-quad reduce ----
    lp0 += __shfl_xor(lp0, 16); lp0 += __shfl_xor(lp0, 32);
    lp1 += __shfl_xor(lp1, 16); lp1 += __shfl_xor(lp1, 32);

    // ---- merge the two KV-split partials (pure adds), store ----
    __syncthreads();
    float* fl = (float*)LDS;   // 64 rows x stride 66 (overlays K/V buffers)
    if (g == 1) {
#pragma unroll
        for (int s = 0; s < 2; s++) {
            if (quad == 0) fl[(wq * 32 + s * 16 + l16) * 66 + 64] = (s ? lp1 : lp0);
#pragma unroll
            for (int r = 0; r < 4; r++) {
                const int row = wq * 32 + s * 16 + quad * 4 + r;
#pragma unroll
                for (int nb = 0; nb < 4; nb++)
                    fl[row * 66 + nb * 16 + l16] = acc[s][nb][r];
            }
        }
    }
    __syncthreads();
    if (g == 0) {
#pragma unroll
        for (int s = 0; s < 2; s++) {
            const float lps = s ? lp1 : lp0;
#pragma unroll
            for (int r = 0; r < 4; r++) {
                const int row = wq * 32 + s * 16 + quad * 4 + r;
                const float l0 = __shfl(lps, quad * 4 + r);
                const float lt = l0 + fl[row * 66 + 64];
                const float inv = 1.0f / lt;
                float* dst = Op + (size_t)(q0 + row) * Dc;
#pragma unroll
                for (int nb = 0; nb < 4; nb++)
                    dst[nb * 16 + l16] = (acc[s][nb][r] + fl[row * 66 + nb * 16 + l16]) * inv;
            }
        }
    }
}

extern "C" void kernel_launch(void* const* d_in, const int* in_sizes, int n_in,
                              void* d_out, int out_size, void* d_ws, size_t ws_size,
                              hipStream_t stream) {
    (void)in_sizes; (void)n_in; (void)ws_size; (void)out_size;
    const float* Q = (const float*)d_in[0];
    const float* K = (const float*)d_in[1];
    const float* V = (const float*)d_in[2];
    const int* wsz = (const int*)d_in[3];
    float* Out = (float*)d_out;

    unsigned short* Kb  = (unsigned short*)((char*)d_ws + KB_OFF);
    unsigned short* Vtb = (unsigned short*)((char*)d_ws + VB_OFF);

    preconv_kernel<<<dim3(3072), dim3(256), 0, stream>>>(K, V, Kb, Vtb);
    // 1024 blocks = 4 blocks/CU x 256 CU, all items resident; static decode.
    dswa_kernel<<<dim3(1024), dim3(256), 0, stream>>>(Q, Kb, Vtb, wsz, Out);
}